// Round 2
// baseline (237.475 us; speedup 1.0000x reference)
//
#include <hip/hip_runtime.h>
#include <hip/hip_bf16.h>

#define N_IN   5023
#define B_SZ   64
#define H_DIM  256
#define NPAD   5120
#define OUT_ELEMS (B_SZ * N_IN * 3)   // 964416

typedef short bf16x8 __attribute__((ext_vector_type(8)));
typedef float f32x4  __attribute__((ext_vector_type(4)));

__device__ inline void async_copy16(const void* g, void* l) {
    __builtin_amdgcn_global_load_lds(
        (const __attribute__((address_space(1))) unsigned int*)g,
        (__attribute__((address_space(3))) unsigned int*)l,
        16, 0, 0);
}

// ---- zero init: out (964416 f32) and l1 (5120 f32) ----
__global__ void zero_kernel(float* __restrict__ out, float* __restrict__ l1) {
    int idx = blockIdx.x * 256 + threadIdx.x;
    if (idx < NPAD) l1[idx] = 0.0f;
    if (idx < OUT_ELEMS) out[idx] = 0.0f;
}

// ---- key_w (5023x256 f32) -> keyb bf16 padded [5120][256] ----
__global__ void conv_key(const float* __restrict__ kw, short* __restrict__ keyb) {
    int idx = blockIdx.x * 256 + threadIdx.x;     // i*256 + h
    if (idx >= NPAD * H_DIM) return;
    int i = idx >> 8, h = idx & 255;
    float v = (i < N_IN) ? kw[(size_t)i * H_DIM + h] : 0.0f;
    ((__hip_bfloat16*)keyb)[idx] = __float2bfloat16(v);
}

// ---- query_w (256x5023 f32) -> qt bf16 [5120][256] transposed *1/16, LDS tiled ----
__global__ void conv_qt(const float* __restrict__ qw, short* __restrict__ qtb) {
    __shared__ float tile[32][33];
    const int hb = blockIdx.x * 32;      // 8 tiles over H
    const int ob = blockIdx.y * 32;      // 160 tiles over NPAD
    const int tx = threadIdx.x;          // 32
    const int ty = threadIdx.y;          // 8
    for (int j = 0; j < 32; j += 8) {
        int h = hb + ty + j;
        int o = ob + tx;
        tile[ty + j][tx] = (o < N_IN) ? qw[(size_t)h * N_IN + o] * 0.0625f : 0.0f;
    }
    __syncthreads();
    __hip_bfloat16* qt = (__hip_bfloat16*)qtb;
    for (int j = 0; j < 32; j += 8) {
        int o = ob + ty + j;
        int h = hb + tx;
        qt[(size_t)o * H_DIM + h] = __float2bfloat16(tile[tx][ty + j]);
    }
}

// ---- GEMM1: score_t[o][i] = sum_h qt[o][h]*key[i][h]; also l1[i] += sum_o |.| ----
// M = N = 5120 (padded), K = 256. Tile 128x128, BK=64, 4 waves (2x2), wave tile 64x64.
__launch_bounds__(256)
__global__ void gemm1(const short* __restrict__ qt, const short* __restrict__ keyb,
                      short* __restrict__ scoreT, float* __restrict__ l1) {
    __shared__ short As[128 * 64];
    __shared__ short Bs[128 * 64];
    const int bm = blockIdx.x, bn = blockIdx.y;
    const int tid = threadIdx.x, lane = tid & 63, wid = tid >> 6;
    const int wave_m = wid >> 1, wave_n = wid & 1;
    const int srow = lane >> 3;            // row within 8-row chunk
    const int scol = (lane & 7) * 8;       // bf16 col offset (8 bf16 = 16B)

    f32x4 acc[4][4];
    const f32x4 zf = {0.f, 0.f, 0.f, 0.f};
    for (int a = 0; a < 4; ++a)
        for (int b = 0; b < 4; ++b) acc[a][b] = zf;

    for (int kb = 0; kb < H_DIM; kb += 64) {
        __syncthreads();
        for (int c = 0; c < 4; ++c) {
            int q = wid * 4 + c;               // 1KB chunk id, 0..15
            int row = q * 8 + srow;
            async_copy16(qt   + (size_t)(bm * 128 + row) * H_DIM + kb + scol, As + q * 512);
            async_copy16(keyb + (size_t)(bn * 128 + row) * H_DIM + kb + scol, Bs + q * 512);
        }
        __syncthreads();
        for (int kk = 0; kk < 64; kk += 32) {
            bf16x8 af[4], bf[4];
            int ko = kk + (lane >> 4) * 8;
            for (int t = 0; t < 4; ++t) {
                af[t] = *(const bf16x8*)(As + (wave_m * 64 + t * 16 + (lane & 15)) * 64 + ko);
                bf[t] = *(const bf16x8*)(Bs + (wave_n * 64 + t * 16 + (lane & 15)) * 64 + ko);
            }
            for (int tm = 0; tm < 4; ++tm)
                for (int tn = 0; tn < 4; ++tn)
                    acc[tm][tn] = __builtin_amdgcn_mfma_f32_16x16x32_bf16(
                        af[tm], bf[tn], acc[tm][tn], 0, 0, 0);
        }
    }

    const int quad = lane >> 4, cit = lane & 15;
    __hip_bfloat16* sc = (__hip_bfloat16*)scoreT;
    for (int tn = 0; tn < 4; ++tn) {
        int ig = bn * 128 + wave_n * 64 + tn * 16 + cit;   // column i
        float p = 0.0f;
        for (int tm = 0; tm < 4; ++tm) {
            int ob = bm * 128 + wave_m * 64 + tm * 16 + quad * 4;
            f32x4 c = acc[tm][tn];
            for (int r = 0; r < 4; ++r) {
                float v = c[r];
                p += fabsf(v);
                sc[(size_t)(ob + r) * NPAD + ig] = __float2bfloat16(v);
            }
        }
        p += __shfl_xor(p, 16);
        p += __shfl_xor(p, 32);
        if (quad == 0) atomicAdd(&l1[ig], p);
    }
}

// ---- VmatT[n=b*3+e][i] = rcp(l1[i]) * sum_d x[b,i,d]*vw[e,d], bf16, padded i ----
__global__ void build_vmat(const float* __restrict__ x, const float* __restrict__ vw,
                           const float* __restrict__ l1, short* __restrict__ vmatT) {
    int idx = blockIdx.x * 256 + threadIdx.x;     // b*NPAD + i
    if (idx >= B_SZ * NPAD) return;
    int b = idx / NPAD, i = idx % NPAD;
    __hip_bfloat16* vt = (__hip_bfloat16*)vmatT;
    if (i < N_IN) {
        const float* xp = x + ((size_t)b * N_IN + i) * 3;
        float x0 = xp[0], x1 = xp[1], x2 = xp[2];
        float r = 1.0f / fmaxf(l1[i], 1e-12f);
        for (int e = 0; e < 3; ++e) {
            float v = x0 * vw[e * 3 + 0] + x1 * vw[e * 3 + 1] + x2 * vw[e * 3 + 2];
            vt[(size_t)(b * 3 + e) * NPAD + i] = __float2bfloat16(v * r);
        }
    } else {
        for (int e = 0; e < 3; ++e)
            vt[(size_t)(b * 3 + e) * NPAD + i] = __float2bfloat16(0.0f);
    }
}

// ---- GEMM2: y[o][n] = sum_i score_t[o][i] * VmatT[n][i]; atomicAdd into out ----
// M=5120, N=192, K=5120. Tile 128x96, BK=64, split-K=8 -> grid (40,2,8)=640 blocks.
// 4 waves as 2x2, wave tile 64x48. acc = 4x3 f32x4 = 48 VGPRs.
__launch_bounds__(256)
__global__ void gemm2(const short* __restrict__ scoreT, const short* __restrict__ vmatT,
                      float* __restrict__ out) {
    __shared__ short As[128 * 64];   // 16 KB
    __shared__ short Bs[96 * 64];    // 12 KB
    const int bm = blockIdx.x;      // o tile (40)
    const int bn = blockIdx.y;      // n tile of 96 (2)
    const int z  = blockIdx.z;      // split-K (8)
    const int tid = threadIdx.x, lane = tid & 63, wid = tid >> 6;
    const int wave_m = wid >> 1, wave_n = wid & 1;
    const int srow = lane >> 3, scol = (lane & 7) * 8;

    f32x4 acc[4][3];
    const f32x4 zf = {0.f, 0.f, 0.f, 0.f};
    for (int a = 0; a < 4; ++a)
        for (int b = 0; b < 3; ++b) acc[a][b] = zf;

    const int kbeg = z * (NPAD / 8), kend = kbeg + (NPAD / 8);   // 640-wide K chunk
    for (int kb = kbeg; kb < kend; kb += 64) {
        __syncthreads();
        for (int c = 0; c < 4; ++c) {
            int q = wid * 4 + c;                   // 0..15
            int row = q * 8 + srow;
            async_copy16(scoreT + (size_t)(bm * 128 + row) * NPAD + kb + scol, As + q * 512);
        }
        for (int c = 0; c < 3; ++c) {
            int q = wid * 3 + c;                   // 0..11
            int row = q * 8 + srow;
            async_copy16(vmatT + (size_t)(bn * 96 + row) * NPAD + kb + scol, Bs + q * 512);
        }
        __syncthreads();
        for (int kk = 0; kk < 64; kk += 32) {
            bf16x8 af[4], bf[3];
            int ko = kk + (lane >> 4) * 8;
            for (int t = 0; t < 4; ++t)
                af[t] = *(const bf16x8*)(As + (wave_m * 64 + t * 16 + (lane & 15)) * 64 + ko);
            for (int t = 0; t < 3; ++t)
                bf[t] = *(const bf16x8*)(Bs + (wave_n * 48 + t * 16 + (lane & 15)) * 64 + ko);
            for (int tm = 0; tm < 4; ++tm)
                for (int tn = 0; tn < 3; ++tn)
                    acc[tm][tn] = __builtin_amdgcn_mfma_f32_16x16x32_bf16(
                        af[tm], bf[tn], acc[tm][tn], 0, 0, 0);
        }
    }

    const int quad = lane >> 4, cit = lane & 15;
    for (int tn = 0; tn < 3; ++tn) {
        int n = bn * 96 + wave_n * 48 + tn * 16 + cit;     // < 192
        int b = n / 3, d = n % 3;
        for (int tm = 0; tm < 4; ++tm) {
            int ob = bm * 128 + wave_m * 64 + tm * 16 + quad * 4;
            f32x4 c = acc[tm][tn];
            for (int r = 0; r < 4; ++r) {
                int o = ob + r;
                if (o < N_IN)
                    atomicAdd(out + (size_t)b * (N_IN * 3) + (size_t)o * 3 + d, c[r]);
            }
        }
    }
}

extern "C" void kernel_launch(void* const* d_in, const int* in_sizes, int n_in,
                              void* d_out, int out_size, void* d_ws, size_t ws_size,
                              hipStream_t stream) {
    const float* x  = (const float*)d_in[0];
    const float* kw = (const float*)d_in[1];
    const float* qw = (const float*)d_in[2];
    const float* vw = (const float*)d_in[3];
    float* out = (float*)d_out;

    char* w = (char*)d_ws;
    short* keyb   = (short*)(w + 0);                      // 5120*256*2  = 2,621,440
    short* qtb    = (short*)(w + 2621440);                // 5120*256*2  = 2,621,440
    short* scoreT = (short*)(w + 5242880);                // 5120*5120*2 = 52,428,800
    float* l1     = (float*)(w + 57671680);               // 5120*4      = 20,480
    short* vmatT  = (short*)(w + 57692160);               // 192*5120*2  = 1,966,080
    // total: 59,658,240 bytes

    zero_kernel<<<(OUT_ELEMS + 255) / 256, 256, 0, stream>>>(out, l1);
    conv_key<<<(NPAD * H_DIM) / 256, 256, 0, stream>>>(kw, keyb);
    conv_qt<<<dim3(H_DIM / 32, NPAD / 32), dim3(32, 8), 0, stream>>>(qw, qtb);
    gemm1<<<dim3(NPAD / 128, NPAD / 128), 256, 0, stream>>>(qtb, keyb, scoreT, l1);
    build_vmat<<<(B_SZ * NPAD) / 256, 256, 0, stream>>>(x, vw, l1, vmatT);
    gemm2<<<dim3(NPAD / 128, 2, 8), 256, 0, stream>>>(scoreT, vmatT, out);
}

// Round 3
// 163.814 us; speedup vs baseline: 1.4497x; 1.4497x over previous
//
#include <hip/hip_runtime.h>
#include <hip/hip_bf16.h>

#define N_IN   5023
#define B_SZ   64
#define H_DIM  256
#define NPAD   5120
#define SPLITK 8
#define OUT_ELEMS (B_SZ * N_IN * 3)   // 964416

typedef short bf16x8 __attribute__((ext_vector_type(8)));
typedef float f32x4  __attribute__((ext_vector_type(4)));

__device__ inline void async_copy16(const void* g, void* l) {
    __builtin_amdgcn_global_load_lds(
        (const __attribute__((address_space(1))) unsigned int*)g,
        (__attribute__((address_space(3))) unsigned int*)l,
        16, 0, 0);
}

// ---- zero init: l1 (5120 f32) ----
__global__ void zero_kernel(float* __restrict__ l1) {
    int idx = blockIdx.x * 256 + threadIdx.x;
    if (idx < NPAD) l1[idx] = 0.0f;
}

// ---- key_w (5023x256 f32) -> keyb bf16 padded [5120][256] ----
__global__ void conv_key(const float* __restrict__ kw, short* __restrict__ keyb) {
    int idx = blockIdx.x * 256 + threadIdx.x;     // i*256 + h
    if (idx >= NPAD * H_DIM) return;
    int i = idx >> 8, h = idx & 255;
    float v = (i < N_IN) ? kw[(size_t)i * H_DIM + h] : 0.0f;
    ((__hip_bfloat16*)keyb)[idx] = __float2bfloat16(v);
}

// ---- query_w (256x5023 f32) -> qt bf16 [5120][256] transposed *1/16, LDS tiled ----
__global__ void conv_qt(const float* __restrict__ qw, short* __restrict__ qtb) {
    __shared__ float tile[32][33];
    const int hb = blockIdx.x * 32;      // 8 tiles over H
    const int ob = blockIdx.y * 32;      // 160 tiles over NPAD
    const int tx = threadIdx.x;          // 32
    const int ty = threadIdx.y;          // 8
    for (int j = 0; j < 32; j += 8) {
        int h = hb + ty + j;
        int o = ob + tx;
        tile[ty + j][tx] = (o < N_IN) ? qw[(size_t)h * N_IN + o] * 0.0625f : 0.0f;
    }
    __syncthreads();
    __hip_bfloat16* qt = (__hip_bfloat16*)qtb;
    for (int j = 0; j < 32; j += 8) {
        int o = ob + ty + j;
        int h = hb + tx;
        qt[(size_t)o * H_DIM + h] = __float2bfloat16(tile[tx][ty + j]);
    }
}

// ---- GEMM1: score_t[o][i] = sum_h qt[o][h]*key[i][h]; also l1[i] += sum_o |.| ----
// M = N = 5120 (padded), K = 256. Tile 128x128, BK=64, 4 waves (2x2), wave tile 64x64.
__launch_bounds__(256)
__global__ void gemm1(const short* __restrict__ qt, const short* __restrict__ keyb,
                      short* __restrict__ scoreT, float* __restrict__ l1) {
    __shared__ short As[128 * 64];
    __shared__ short Bs[128 * 64];
    const int bm = blockIdx.x, bn = blockIdx.y;
    const int tid = threadIdx.x, lane = tid & 63, wid = tid >> 6;
    const int wave_m = wid >> 1, wave_n = wid & 1;
    const int srow = lane >> 3;            // row within 8-row chunk
    const int scol = (lane & 7) * 8;       // bf16 col offset (8 bf16 = 16B)

    f32x4 acc[4][4];
    const f32x4 zf = {0.f, 0.f, 0.f, 0.f};
    for (int a = 0; a < 4; ++a)
        for (int b = 0; b < 4; ++b) acc[a][b] = zf;

    for (int kb = 0; kb < H_DIM; kb += 64) {
        __syncthreads();
        for (int c = 0; c < 4; ++c) {
            int q = wid * 4 + c;               // 1KB chunk id, 0..15
            int row = q * 8 + srow;
            async_copy16(qt   + (size_t)(bm * 128 + row) * H_DIM + kb + scol, As + q * 512);
            async_copy16(keyb + (size_t)(bn * 128 + row) * H_DIM + kb + scol, Bs + q * 512);
        }
        __syncthreads();
        for (int kk = 0; kk < 64; kk += 32) {
            bf16x8 af[4], bf[4];
            int ko = kk + (lane >> 4) * 8;
            for (int t = 0; t < 4; ++t) {
                af[t] = *(const bf16x8*)(As + (wave_m * 64 + t * 16 + (lane & 15)) * 64 + ko);
                bf[t] = *(const bf16x8*)(Bs + (wave_n * 64 + t * 16 + (lane & 15)) * 64 + ko);
            }
            for (int tm = 0; tm < 4; ++tm)
                for (int tn = 0; tn < 4; ++tn)
                    acc[tm][tn] = __builtin_amdgcn_mfma_f32_16x16x32_bf16(
                        af[tm], bf[tn], acc[tm][tn], 0, 0, 0);
        }
    }

    const int quad = lane >> 4, cit = lane & 15;
    __hip_bfloat16* sc = (__hip_bfloat16*)scoreT;
    for (int tn = 0; tn < 4; ++tn) {
        int ig = bn * 128 + wave_n * 64 + tn * 16 + cit;   // column i
        float p = 0.0f;
        for (int tm = 0; tm < 4; ++tm) {
            int ob = bm * 128 + wave_m * 64 + tm * 16 + quad * 4;
            f32x4 c = acc[tm][tn];
            for (int r = 0; r < 4; ++r) {
                float v = c[r];
                p += fabsf(v);
                sc[(size_t)(ob + r) * NPAD + ig] = __float2bfloat16(v);
            }
        }
        p += __shfl_xor(p, 16);
        p += __shfl_xor(p, 32);
        if (quad == 0) atomicAdd(&l1[ig], p);
    }
}

// ---- VmatT[n=b*3+e][i] = rcp(l1[i]) * sum_d x[b,i,d]*vw[e,d], bf16, padded i ----
__global__ void build_vmat(const float* __restrict__ x, const float* __restrict__ vw,
                           const float* __restrict__ l1, short* __restrict__ vmatT) {
    int idx = blockIdx.x * 256 + threadIdx.x;     // b*NPAD + i
    if (idx >= B_SZ * NPAD) return;
    int b = idx / NPAD, i = idx % NPAD;
    __hip_bfloat16* vt = (__hip_bfloat16*)vmatT;
    if (i < N_IN) {
        const float* xp = x + ((size_t)b * N_IN + i) * 3;
        float x0 = xp[0], x1 = xp[1], x2 = xp[2];
        float r = 1.0f / fmaxf(l1[i], 1e-12f);
        for (int e = 0; e < 3; ++e) {
            float v = x0 * vw[e * 3 + 0] + x1 * vw[e * 3 + 1] + x2 * vw[e * 3 + 2];
            vt[(size_t)(b * 3 + e) * NPAD + i] = __float2bfloat16(v * r);
        }
    } else {
        for (int e = 0; e < 3; ++e)
            vt[(size_t)(b * 3 + e) * NPAD + i] = __float2bfloat16(0.0f);
    }
}

// ---- GEMM2: part[z][o][n] = sum_{i in z-chunk} score_t[o][i] * VmatT[n][i] ----
// M=5120, N=192, K=5120. Tile 128x96, BK=64, split-K=8 -> grid (40,2,8)=640 blocks.
// Plain coalesced stores into per-z partials (NO atomics).
__launch_bounds__(256)
__global__ void gemm2(const short* __restrict__ scoreT, const short* __restrict__ vmatT,
                      float* __restrict__ part) {
    __shared__ short As[128 * 64];   // 16 KB
    __shared__ short Bs[96 * 64];    // 12 KB
    const int bm = blockIdx.x;      // o tile (40)
    const int bn = blockIdx.y;      // n tile of 96 (2)
    const int z  = blockIdx.z;      // split-K (8)
    const int tid = threadIdx.x, lane = tid & 63, wid = tid >> 6;
    const int wave_m = wid >> 1, wave_n = wid & 1;
    const int srow = lane >> 3, scol = (lane & 7) * 8;

    f32x4 acc[4][3];
    const f32x4 zf = {0.f, 0.f, 0.f, 0.f};
    for (int a = 0; a < 4; ++a)
        for (int b = 0; b < 3; ++b) acc[a][b] = zf;

    const int kbeg = z * (NPAD / SPLITK), kend = kbeg + (NPAD / SPLITK);   // 640-wide chunk
    for (int kb = kbeg; kb < kend; kb += 64) {
        __syncthreads();
        for (int c = 0; c < 4; ++c) {
            int q = wid * 4 + c;                   // 0..15
            int row = q * 8 + srow;
            async_copy16(scoreT + (size_t)(bm * 128 + row) * NPAD + kb + scol, As + q * 512);
        }
        for (int c = 0; c < 3; ++c) {
            int q = wid * 3 + c;                   // 0..11
            int row = q * 8 + srow;
            async_copy16(vmatT + (size_t)(bn * 96 + row) * NPAD + kb + scol, Bs + q * 512);
        }
        __syncthreads();
        for (int kk = 0; kk < 64; kk += 32) {
            bf16x8 af[4], bf[3];
            int ko = kk + (lane >> 4) * 8;
            for (int t = 0; t < 4; ++t)
                af[t] = *(const bf16x8*)(As + (wave_m * 64 + t * 16 + (lane & 15)) * 64 + ko);
            for (int t = 0; t < 3; ++t)
                bf[t] = *(const bf16x8*)(Bs + (wave_n * 48 + t * 16 + (lane & 15)) * 64 + ko);
            for (int tm = 0; tm < 4; ++tm)
                for (int tn = 0; tn < 3; ++tn)
                    acc[tm][tn] = __builtin_amdgcn_mfma_f32_16x16x32_bf16(
                        af[tm], bf[tn], acc[tm][tn], 0, 0, 0);
        }
    }

    const int quad = lane >> 4, cit = lane & 15;
    float* pz = part + (size_t)z * (NPAD * 192);
    for (int tn = 0; tn < 3; ++tn) {
        int n = bn * 96 + wave_n * 48 + tn * 16 + cit;     // < 192
        for (int tm = 0; tm < 4; ++tm) {
            int ob = bm * 128 + wave_m * 64 + tm * 16 + quad * 4;
            f32x4 c = acc[tm][tn];
            for (int r = 0; r < 4; ++r)
                pz[(size_t)(ob + r) * 192 + n] = c[r];
        }
    }
}

// ---- reduce: out[b][o][d] = sum_z part[z][o][b*3+d]  (trims o >= N_IN) ----
__global__ void reduce_out(const float* __restrict__ part, float* __restrict__ out) {
    int idx = blockIdx.x * 256 + threadIdx.x;
    if (idx >= OUT_ELEMS) return;
    int b = idx / (N_IN * 3);
    int rem = idx - b * (N_IN * 3);
    int o = rem / 3, d = rem - o * 3;
    size_t off = (size_t)o * 192 + b * 3 + d;
    float s = 0.0f;
    for (int z = 0; z < SPLITK; ++z)
        s += part[(size_t)z * (NPAD * 192) + off];
    out[idx] = s;
}

extern "C" void kernel_launch(void* const* d_in, const int* in_sizes, int n_in,
                              void* d_out, int out_size, void* d_ws, size_t ws_size,
                              hipStream_t stream) {
    const float* x  = (const float*)d_in[0];
    const float* kw = (const float*)d_in[1];
    const float* qw = (const float*)d_in[2];
    const float* vw = (const float*)d_in[3];
    float* out = (float*)d_out;

    char* w = (char*)d_ws;
    short* keyb   = (short*)(w + 0);                      // 5120*256*2  = 2,621,440
    short* qtb    = (short*)(w + 2621440);                // 5120*256*2  = 2,621,440
    short* scoreT = (short*)(w + 5242880);                // 5120*5120*2 = 52,428,800
    float* l1     = (float*)(w + 57671680);               // 5120*4      = 20,480
    short* vmatT  = (short*)(w + 57692160);               // 192*5120*2  = 1,966,080
    float* part   = (float*)(w + 59658240);               // 8*5120*192*4 = 31,457,280
    // total: 91,115,520 bytes

    zero_kernel<<<NPAD / 256, 256, 0, stream>>>(l1);
    conv_key<<<(NPAD * H_DIM) / 256, 256, 0, stream>>>(kw, keyb);
    conv_qt<<<dim3(H_DIM / 32, NPAD / 32), dim3(32, 8), 0, stream>>>(qw, qtb);
    gemm1<<<dim3(NPAD / 128, NPAD / 128), 256, 0, stream>>>(qtb, keyb, scoreT, l1);
    build_vmat<<<(B_SZ * NPAD) / 256, 256, 0, stream>>>(x, vw, l1, vmatT);
    gemm2<<<dim3(NPAD / 128, 2, SPLITK), 256, 0, stream>>>(scoreT, vmatT, part);
    reduce_out<<<(OUT_ELEMS + 255) / 256, 256, 0, stream>>>(part, out);
}

// Round 4
// 131.923 us; speedup vs baseline: 1.8001x; 1.2417x over previous
//
#include <hip/hip_runtime.h>
#include <hip/hip_bf16.h>

#define N_IN   5023
#define B_SZ   64
#define H_DIM  256
#define NPAD   5120
#define SPLITK 8
#define OUT_ELEMS (B_SZ * N_IN * 3)   // 964416

typedef short bf16x8 __attribute__((ext_vector_type(8)));
typedef float f32x4  __attribute__((ext_vector_type(4)));

__device__ inline void async_copy16(const void* g, void* l) {
    __builtin_amdgcn_global_load_lds(
        (const __attribute__((address_space(1))) unsigned int*)g,
        (__attribute__((address_space(3))) unsigned int*)l,
        16, 0, 0);
}

// ---- zero init: l1 (5120 f32) ----
__global__ void zero_kernel(float* __restrict__ l1) {
    int idx = blockIdx.x * 256 + threadIdx.x;
    if (idx < NPAD) l1[idx] = 0.0f;
}

// ---- key_w (5023x256 f32) -> keyb bf16 padded [5120][256] ----
__global__ void conv_key(const float* __restrict__ kw, short* __restrict__ keyb) {
    int idx = blockIdx.x * 256 + threadIdx.x;     // i*256 + h
    if (idx >= NPAD * H_DIM) return;
    int i = idx >> 8, h = idx & 255;
    float v = (i < N_IN) ? kw[(size_t)i * H_DIM + h] : 0.0f;
    ((__hip_bfloat16*)keyb)[idx] = __float2bfloat16(v);
}

// ---- query_w (256x5023 f32) -> qt bf16 [5120][256] transposed *1/16, LDS tiled ----
__global__ void conv_qt(const float* __restrict__ qw, short* __restrict__ qtb) {
    __shared__ float tile[32][33];
    const int hb = blockIdx.x * 32;      // 8 tiles over H
    const int ob = blockIdx.y * 32;      // 160 tiles over NPAD
    const int tx = threadIdx.x;          // 32
    const int ty = threadIdx.y;          // 8
    for (int j = 0; j < 32; j += 8) {
        int h = hb + ty + j;
        int o = ob + tx;
        tile[ty + j][tx] = (o < N_IN) ? qw[(size_t)h * N_IN + o] * 0.0625f : 0.0f;
    }
    __syncthreads();
    __hip_bfloat16* qt = (__hip_bfloat16*)qtb;
    for (int j = 0; j < 32; j += 8) {
        int o = ob + ty + j;
        int h = hb + tx;
        qt[(size_t)o * H_DIM + h] = __float2bfloat16(tile[tx][ty + j]);
    }
}

// ---- GEMM1: score_t[o][i] = sum_h qt[o][h]*key[i][h]; also l1[i] += sum_o |.| ----
// M = N = 5120 (padded), K = 256. Tile 128x128, BK=64, 4 waves (2x2), wave tile 64x64.
__launch_bounds__(256)
__global__ void gemm1(const short* __restrict__ qt, const short* __restrict__ keyb,
                      short* __restrict__ scoreT, float* __restrict__ l1) {
    __shared__ short As[128 * 64];
    __shared__ short Bs[128 * 64];
    const int bm = blockIdx.x, bn = blockIdx.y;
    const int tid = threadIdx.x, lane = tid & 63, wid = tid >> 6;
    const int wave_m = wid >> 1, wave_n = wid & 1;
    const int srow = lane >> 3;            // row within 8-row chunk
    const int scol = (lane & 7) * 8;       // bf16 col offset (8 bf16 = 16B)

    f32x4 acc[4][4];
    const f32x4 zf = {0.f, 0.f, 0.f, 0.f};
    for (int a = 0; a < 4; ++a)
        for (int b = 0; b < 4; ++b) acc[a][b] = zf;

    for (int kb = 0; kb < H_DIM; kb += 64) {
        __syncthreads();
        for (int c = 0; c < 4; ++c) {
            int q = wid * 4 + c;               // 1KB chunk id, 0..15
            int row = q * 8 + srow;
            async_copy16(qt   + (size_t)(bm * 128 + row) * H_DIM + kb + scol, As + q * 512);
            async_copy16(keyb + (size_t)(bn * 128 + row) * H_DIM + kb + scol, Bs + q * 512);
        }
        __syncthreads();
        for (int kk = 0; kk < 64; kk += 32) {
            bf16x8 af[4], bf[4];
            int ko = kk + (lane >> 4) * 8;
            for (int t = 0; t < 4; ++t) {
                af[t] = *(const bf16x8*)(As + (wave_m * 64 + t * 16 + (lane & 15)) * 64 + ko);
                bf[t] = *(const bf16x8*)(Bs + (wave_n * 64 + t * 16 + (lane & 15)) * 64 + ko);
            }
            for (int tm = 0; tm < 4; ++tm)
                for (int tn = 0; tn < 4; ++tn)
                    acc[tm][tn] = __builtin_amdgcn_mfma_f32_16x16x32_bf16(
                        af[tm], bf[tn], acc[tm][tn], 0, 0, 0);
        }
    }

    const int quad = lane >> 4, cit = lane & 15;
    __hip_bfloat16* sc = (__hip_bfloat16*)scoreT;
    for (int tn = 0; tn < 4; ++tn) {
        int ig = bn * 128 + wave_n * 64 + tn * 16 + cit;   // column i
        float p = 0.0f;
        for (int tm = 0; tm < 4; ++tm) {
            int ob = bm * 128 + wave_m * 64 + tm * 16 + quad * 4;
            f32x4 c = acc[tm][tn];
            for (int r = 0; r < 4; ++r) {
                float v = c[r];
                p += fabsf(v);
                sc[(size_t)(ob + r) * NPAD + ig] = __float2bfloat16(v);
            }
        }
        p += __shfl_xor(p, 16);
        p += __shfl_xor(p, 32);
        if (quad == 0) atomicAdd(&l1[ig], p);
    }
}

// ---- VmatT[n=b*3+e][i] = rcp(l1[i]) * sum_d x[b,i,d]*vw[e,d], bf16, padded i ----
__global__ void build_vmat(const float* __restrict__ x, const float* __restrict__ vw,
                           const float* __restrict__ l1, short* __restrict__ vmatT) {
    int idx = blockIdx.x * 256 + threadIdx.x;     // b*NPAD + i
    if (idx >= B_SZ * NPAD) return;
    int b = idx / NPAD, i = idx % NPAD;
    __hip_bfloat16* vt = (__hip_bfloat16*)vmatT;
    if (i < N_IN) {
        const float* xp = x + ((size_t)b * N_IN + i) * 3;
        float x0 = xp[0], x1 = xp[1], x2 = xp[2];
        float r = 1.0f / fmaxf(l1[i], 1e-12f);
        for (int e = 0; e < 3; ++e) {
            float v = x0 * vw[e * 3 + 0] + x1 * vw[e * 3 + 1] + x2 * vw[e * 3 + 2];
            vt[(size_t)(b * 3 + e) * NPAD + i] = __float2bfloat16(v * r);
        }
    } else {
        for (int e = 0; e < 3; ++e)
            vt[(size_t)(b * 3 + e) * NPAD + i] = __float2bfloat16(0.0f);
    }
}

// ---- GEMM2: part[z][o][n] = sum_{i in z-chunk} score_t[o][i] * VmatT[n][i] ----
// M=5120, N=192, K=5120. Tile 128x96, BK=64, split-K=8 -> grid (40,2,8)=640 blocks.
// Plain coalesced stores into per-z partials (NO atomics).
__launch_bounds__(256)
__global__ void gemm2(const short* __restrict__ scoreT, const short* __restrict__ vmatT,
                      float* __restrict__ part) {
    __shared__ short As[128 * 64];   // 16 KB
    __shared__ short Bs[96 * 64];    // 12 KB
    const int bm = blockIdx.x;      // o tile (40)
    const int bn = blockIdx.y;      // n tile of 96 (2)
    const int z  = blockIdx.z;      // split-K (8)
    const int tid = threadIdx.x, lane = tid & 63, wid = tid >> 6;
    const int wave_m = wid >> 1, wave_n = wid & 1;
    const int srow = lane >> 3, scol = (lane & 7) * 8;

    f32x4 acc[4][3];
    const f32x4 zf = {0.f, 0.f, 0.f, 0.f};
    for (int a = 0; a < 4; ++a)
        for (int b = 0; b < 3; ++b) acc[a][b] = zf;

    const int kbeg = z * (NPAD / SPLITK), kend = kbeg + (NPAD / SPLITK);   // 640-wide chunk
    for (int kb = kbeg; kb < kend; kb += 64) {
        __syncthreads();
        for (int c = 0; c < 4; ++c) {
            int q = wid * 4 + c;                   // 0..15
            int row = q * 8 + srow;
            async_copy16(scoreT + (size_t)(bm * 128 + row) * NPAD + kb + scol, As + q * 512);
        }
        for (int c = 0; c < 3; ++c) {
            int q = wid * 3 + c;                   // 0..11
            int row = q * 8 + srow;
            async_copy16(vmatT + (size_t)(bn * 96 + row) * NPAD + kb + scol, Bs + q * 512);
        }
        __syncthreads();
        for (int kk = 0; kk < 64; kk += 32) {
            bf16x8 af[4], bf[3];
            int ko = kk + (lane >> 4) * 8;
            for (int t = 0; t < 4; ++t)
                af[t] = *(const bf16x8*)(As + (wave_m * 64 + t * 16 + (lane & 15)) * 64 + ko);
            for (int t = 0; t < 3; ++t)
                bf[t] = *(const bf16x8*)(Bs + (wave_n * 48 + t * 16 + (lane & 15)) * 64 + ko);
            for (int tm = 0; tm < 4; ++tm)
                for (int tn = 0; tn < 3; ++tn)
                    acc[tm][tn] = __builtin_amdgcn_mfma_f32_16x16x32_bf16(
                        af[tm], bf[tn], acc[tm][tn], 0, 0, 0);
        }
    }

    const int quad = lane >> 4, cit = lane & 15;
    float* pz = part + (size_t)z * (NPAD * 192);
    for (int tn = 0; tn < 3; ++tn) {
        int n = bn * 96 + wave_n * 48 + tn * 16 + cit;     // < 192
        for (int tm = 0; tm < 4; ++tm) {
            int ob = bm * 128 + wave_m * 64 + tm * 16 + quad * 4;
            f32x4 c = acc[tm][tn];
            for (int r = 0; r < 4; ++r)
                pz[(size_t)(ob + r) * 192 + n] = c[r];
        }
    }
}

// ---- reduce: out[b][o][d] = sum_z part[z][o][b*3+d], LDS-transposed coalesced ----
// Block: 16 o-rows x 192 n = 3072 elems. Grid: 320 blocks. Read f4-coalesced,
// write 48-float contiguous runs per b.
#define RO_ROWS 16
#define RO_PITCH 196   // floats; mult of 4 for f4 alignment, mod 32 = 4
__global__ void reduce_out(const float* __restrict__ part, float* __restrict__ out) {
    __shared__ float lds[RO_ROWS * RO_PITCH];
    const int ob = blockIdx.x * RO_ROWS;
    const int t = threadIdx.x;

    // phase 1: sum 8 z-slices, f4-coalesced. 3072 floats = 768 f4 = 3 iters.
    for (int it = 0; it < 3; ++it) {
        int f4 = it * 256 + t;                 // 0..767
        int o  = f4 / 48;                      // 48 f4 per 192-float row
        int n4 = f4 % 48;
        f32x4 s = {0.f, 0.f, 0.f, 0.f};
        size_t base = (size_t)(ob + o) * 192 + n4 * 4;
        for (int z = 0; z < SPLITK; ++z) {
            f32x4 v = *(const f32x4*)(part + (size_t)z * (NPAD * 192) + base);
            s.x += v.x; s.y += v.y; s.z += v.z; s.w += v.w;
        }
        *(f32x4*)(lds + o * RO_PITCH + n4 * 4) = s;
    }
    __syncthreads();

    // phase 2: write out[b][o][d] in 48-float contiguous runs per b.
    for (int it = 0; it < 12; ++it) {
        int flat = it * 256 + t;               // 0..3071
        int b = flat / 48;                     // 64 b's x 48 (16 o x 3 d)
        int w = flat % 48;
        int o = w / 3, d = w % 3;
        int og = ob + o;
        if (og < N_IN)
            out[(size_t)b * (N_IN * 3) + (size_t)og * 3 + d] =
                lds[o * RO_PITCH + b * 3 + d];
    }
}

extern "C" void kernel_launch(void* const* d_in, const int* in_sizes, int n_in,
                              void* d_out, int out_size, void* d_ws, size_t ws_size,
                              hipStream_t stream) {
    const float* x  = (const float*)d_in[0];
    const float* kw = (const float*)d_in[1];
    const float* qw = (const float*)d_in[2];
    const float* vw = (const float*)d_in[3];
    float* out = (float*)d_out;

    char* w = (char*)d_ws;
    short* keyb   = (short*)(w + 0);                      // 5120*256*2  = 2,621,440
    short* qtb    = (short*)(w + 2621440);                // 5120*256*2  = 2,621,440
    short* scoreT = (short*)(w + 5242880);                // 5120*5120*2 = 52,428,800
    float* l1     = (float*)(w + 57671680);               // 5120*4      = 20,480
    short* vmatT  = (short*)(w + 57692160);               // 192*5120*2  = 1,966,080
    float* part   = (float*)(w + 59658240);               // 8*5120*192*4 = 31,457,280
    // total: 91,115,520 bytes

    zero_kernel<<<NPAD / 256, 256, 0, stream>>>(l1);
    conv_key<<<(NPAD * H_DIM) / 256, 256, 0, stream>>>(kw, keyb);
    conv_qt<<<dim3(H_DIM / 32, NPAD / 32), dim3(32, 8), 0, stream>>>(qw, qtb);
    gemm1<<<dim3(NPAD / 128, NPAD / 128), 256, 0, stream>>>(qtb, keyb, scoreT, l1);
    build_vmat<<<(B_SZ * NPAD) / 256, 256, 0, stream>>>(x, vw, l1, vmatT);
    gemm2<<<dim3(NPAD / 128, 2, SPLITK), 256, 0, stream>>>(scoreT, vmatT, part);
    reduce_out<<<NPAD / RO_ROWS, 256, 0, stream>>>(part, out);
}

// Round 5
// 115.129 us; speedup vs baseline: 2.0627x; 1.1459x over previous
//
#include <hip/hip_runtime.h>
#include <hip/hip_bf16.h>

#define N_IN   5023
#define B_SZ   64
#define H_DIM  256
#define NPAD   5120
#define NBD    192          // B_SZ * 3
#define SPLITZ 20           // gemm3 split-K slices (K-chunk 256 = 4 x BK64)
#define OUT_ELEMS (B_SZ * N_IN * 3)   // 964416

typedef short bf16x8 __attribute__((ext_vector_type(8)));
typedef float f32x4  __attribute__((ext_vector_type(4)));

__device__ inline void async_copy16(const void* g, void* l) {
    __builtin_amdgcn_global_load_lds(
        (const __attribute__((address_space(1))) unsigned int*)g,
        (__attribute__((address_space(3))) unsigned int*)l,
        16, 0, 0);
}

// ---- key_w (5023x256 f32) -> keyb bf16 [5120][256] AND keyT bf16 [256][5120];
//      also zeroes l1. LDS-tiled transpose, both sides coalesced. ----
__global__ void conv_key_all(const float* __restrict__ kw, short* __restrict__ keyb,
                             short* __restrict__ keyT, float* __restrict__ l1) {
    __shared__ float tile[32][33];
    const int hb = blockIdx.x * 32;      // 8 tiles over H
    const int ib = blockIdx.y * 32;      // 160 tiles over NPAD
    const int tx = threadIdx.x;          // 32
    const int ty = threadIdx.y;          // 8
    __hip_bfloat16* kb = (__hip_bfloat16*)keyb;
    __hip_bfloat16* kt = (__hip_bfloat16*)keyT;
    for (int j = 0; j < 32; j += 8) {
        int i = ib + ty + j;
        int h = hb + tx;
        float v = (i < N_IN) ? kw[(size_t)i * H_DIM + h] : 0.0f;
        tile[ty + j][tx] = v;                         // tile[i_local][h_local]
        kb[(size_t)i * H_DIM + h] = __float2bfloat16(v);
    }
    __syncthreads();
    for (int j = 0; j < 32; j += 8) {
        int h = hb + ty + j;
        int i = ib + tx;
        kt[(size_t)h * NPAD + i] = __float2bfloat16(tile[tx][ty + j]);
    }
    if (blockIdx.x == 0 && ty == 0) l1[ib + tx] = 0.0f;
}

// ---- query_w (256x5023 f32) -> qt bf16 [5120][256] transposed *1/16, LDS tiled ----
__global__ void conv_qt(const float* __restrict__ qw, short* __restrict__ qtb) {
    __shared__ float tile[32][33];
    const int hb = blockIdx.x * 32;
    const int ob = blockIdx.y * 32;
    const int tx = threadIdx.x;
    const int ty = threadIdx.y;
    for (int j = 0; j < 32; j += 8) {
        int h = hb + ty + j;
        int o = ob + tx;
        tile[ty + j][tx] = (o < N_IN) ? qw[(size_t)h * N_IN + o] * 0.0625f : 0.0f;
    }
    __syncthreads();
    __hip_bfloat16* qt = (__hip_bfloat16*)qtb;
    for (int j = 0; j < 32; j += 8) {
        int o = ob + ty + j;
        int h = hb + tx;
        qt[(size_t)o * H_DIM + h] = __float2bfloat16(tile[tx][ty + j]);
    }
}

// ---- GEMM_L1: l1[i] = sum_o |sum_h qt[o][h]*key[i][h]|  (NO score store) ----
// M = N = 5120, K = 256. Tile 128x128, BK=64, 4 waves 2x2, wave tile 64x64.
__launch_bounds__(256)
__global__ void gemm_l1(const short* __restrict__ qt, const short* __restrict__ keyb,
                        float* __restrict__ l1) {
    __shared__ short As[128 * 64];
    __shared__ short Bs[128 * 64];
    const int bm = blockIdx.x, bn = blockIdx.y;
    const int tid = threadIdx.x, lane = tid & 63, wid = tid >> 6;
    const int wave_m = wid >> 1, wave_n = wid & 1;
    const int srow = lane >> 3;
    const int scol = (lane & 7) * 8;

    f32x4 acc[4][4];
    const f32x4 zf = {0.f, 0.f, 0.f, 0.f};
    for (int a = 0; a < 4; ++a)
        for (int b = 0; b < 4; ++b) acc[a][b] = zf;

    for (int kb = 0; kb < H_DIM; kb += 64) {
        __syncthreads();
        for (int c = 0; c < 4; ++c) {
            int q = wid * 4 + c;
            int row = q * 8 + srow;
            async_copy16(qt   + (size_t)(bm * 128 + row) * H_DIM + kb + scol, As + q * 512);
            async_copy16(keyb + (size_t)(bn * 128 + row) * H_DIM + kb + scol, Bs + q * 512);
        }
        __syncthreads();
        for (int kk = 0; kk < 64; kk += 32) {
            bf16x8 af[4], bf[4];
            int ko = kk + (lane >> 4) * 8;
            for (int t = 0; t < 4; ++t) {
                af[t] = *(const bf16x8*)(As + (wave_m * 64 + t * 16 + (lane & 15)) * 64 + ko);
                bf[t] = *(const bf16x8*)(Bs + (wave_n * 64 + t * 16 + (lane & 15)) * 64 + ko);
            }
            for (int tm = 0; tm < 4; ++tm)
                for (int tn = 0; tn < 4; ++tn)
                    acc[tm][tn] = __builtin_amdgcn_mfma_f32_16x16x32_bf16(
                        af[tm], bf[tn], acc[tm][tn], 0, 0, 0);
        }
    }

    const int quad = lane >> 4, cit = lane & 15;
    for (int tn = 0; tn < 4; ++tn) {
        int ig = bn * 128 + wave_n * 64 + tn * 16 + cit;   // column i
        float p = 0.0f;
        for (int tm = 0; tm < 4; ++tm) {
            f32x4 c = acc[tm][tn];
            p += fabsf(c.x) + fabsf(c.y) + fabsf(c.z) + fabsf(c.w);
        }
        p += __shfl_xor(p, 16);
        p += __shfl_xor(p, 32);
        if (quad == 0) atomicAdd(&l1[ig], p);
    }
}

// ---- vmatT[bd=b*3+e][i] = (1/max(l1[i],eps)) * sum_d x[b,i,d]*vw[e,d], bf16 ----
__global__ void build_vmat(const float* __restrict__ x, const float* __restrict__ vw,
                           const float* __restrict__ l1, short* __restrict__ vmatT) {
    int idx = blockIdx.x * 256 + threadIdx.x;     // b*NPAD + i
    if (idx >= B_SZ * NPAD) return;
    int b = idx / NPAD, i = idx % NPAD;
    __hip_bfloat16* vt = (__hip_bfloat16*)vmatT;
    if (i < N_IN) {
        const float* xp = x + ((size_t)b * N_IN + i) * 3;
        float x0 = xp[0], x1 = xp[1], x2 = xp[2];
        float r = 1.0f / fmaxf(l1[i], 1e-12f);
        for (int e = 0; e < 3; ++e) {
            float v = x0 * vw[e * 3 + 0] + x1 * vw[e * 3 + 1] + x2 * vw[e * 3 + 2];
            vt[(size_t)(b * 3 + e) * NPAD + i] = __float2bfloat16(v * r);
        }
    } else {
        for (int e = 0; e < 3; ++e)
            vt[(size_t)(b * 3 + e) * NPAD + i] = __float2bfloat16(0.0f);
    }
}

// ---- GEMM3: part2[z][bd][h] = sum_{i in z-chunk} vmatT[bd][i] * keyT[h][i] ----
// M=192(bd), N=64(h per block), K-chunk 256. Grid (4 h-tiles, 20 z) = 80 blocks.
// Waves 2x2: wave tile 96x32 -> acc[6][2].
__launch_bounds__(256)
__global__ void gemm3(const short* __restrict__ vmatT, const short* __restrict__ keyT,
                      float* __restrict__ part2) {
    __shared__ short As[192 * 64];   // 24 KB (all 192 bd rows)
    __shared__ short Bs[64 * 64];    // 8 KB
    const int bh = blockIdx.x;       // h tile (4)
    const int z  = blockIdx.y;       // split-K (20)
    const int tid = threadIdx.x, lane = tid & 63, wid = tid >> 6;
    const int wave_m = wid >> 1, wave_n = wid & 1;
    const int srow = lane >> 3, scol = (lane & 7) * 8;
    const int quad = lane >> 4, cit = lane & 15;

    f32x4 acc[6][2];
    const f32x4 zf = {0.f, 0.f, 0.f, 0.f};
    for (int a = 0; a < 6; ++a)
        for (int b = 0; b < 2; ++b) acc[a][b] = zf;

    const int kbeg = z * (NPAD / SPLITZ);            // 256-wide chunk
    for (int kb = kbeg; kb < kbeg + NPAD / SPLITZ; kb += 64) {
        __syncthreads();
        for (int c = 0; c < 6; ++c) {
            int q = wid * 6 + c;                     // 0..23
            int row = q * 8 + srow;                  // bd row
            async_copy16(vmatT + (size_t)row * NPAD + kb + scol, As + q * 512);
        }
        for (int c = 0; c < 2; ++c) {
            int q = wid * 2 + c;                     // 0..7
            int row = q * 8 + srow;                  // h row local
            async_copy16(keyT + (size_t)(bh * 64 + row) * NPAD + kb + scol, Bs + q * 512);
        }
        __syncthreads();
        for (int kk = 0; kk < 64; kk += 32) {
            bf16x8 af[6], bf[2];
            int ko = kk + quad * 8;
            for (int t = 0; t < 6; ++t)
                af[t] = *(const bf16x8*)(As + (wave_m * 96 + t * 16 + cit) * 64 + ko);
            for (int t = 0; t < 2; ++t)
                bf[t] = *(const bf16x8*)(Bs + (wave_n * 32 + t * 16 + cit) * 64 + ko);
            for (int tm = 0; tm < 6; ++tm)
                for (int tn = 0; tn < 2; ++tn)
                    acc[tm][tn] = __builtin_amdgcn_mfma_f32_16x16x32_bf16(
                        af[tm], bf[tn], acc[tm][tn], 0, 0, 0);
        }
    }

    float* pz = part2 + (size_t)z * (NBD * H_DIM);
    for (int tn = 0; tn < 2; ++tn) {
        int h = bh * 64 + wave_n * 32 + tn * 16 + cit;
        for (int tm = 0; tm < 6; ++tm) {
            int bd0 = wave_m * 96 + tm * 16 + quad * 4;
            f32x4 c = acc[tm][tn];
            for (int r = 0; r < 4; ++r)
                pz[(size_t)(bd0 + r) * H_DIM + h] = c[r];
        }
    }
}

// ---- reduce_T: T[bd][h] = bf16(sum_z part2[z][bd][h]) ----
__global__ void reduce_T(const float* __restrict__ part2, short* __restrict__ T) {
    int idx = blockIdx.x * 256 + threadIdx.x;     // < 49152
    float s = 0.0f;
    for (int z = 0; z < SPLITZ; ++z)
        s += part2[(size_t)z * (NBD * H_DIM) + idx];
    ((__hip_bfloat16*)T)[idx] = __float2bfloat16(s);
}

// ---- GEMM4: y[o][bd] = sum_h qt[o][h] * T[bd][h]; out[b][o][d] via LDS transpose ----
// M=5120 (80 tiles of 64), N=192, K=256. Waves 2x2: wave tile 32x96 -> acc[2][6].
#define CS_PITCH 196
__launch_bounds__(256)
__global__ void gemm4(const short* __restrict__ qt, const short* __restrict__ T,
                      float* __restrict__ out) {
    __shared__ char smem[64 * CS_PITCH * 4];   // 50176 B; staging uses first 32 KB
    short* As = (short*)smem;                  // 64*64
    short* Bs = As + 64 * 64;                  // 192*64
    const int bm = blockIdx.x;                 // 80
    const int tid = threadIdx.x, lane = tid & 63, wid = tid >> 6;
    const int wave_m = wid >> 1, wave_n = wid & 1;
    const int srow = lane >> 3, scol = (lane & 7) * 8;
    const int quad = lane >> 4, cit = lane & 15;

    f32x4 acc[2][6];
    const f32x4 zf = {0.f, 0.f, 0.f, 0.f};
    for (int a = 0; a < 2; ++a)
        for (int b = 0; b < 6; ++b) acc[a][b] = zf;

    for (int kb = 0; kb < H_DIM; kb += 64) {
        __syncthreads();
        for (int c = 0; c < 2; ++c) {
            int q = wid * 2 + c;                     // 0..7
            int row = q * 8 + srow;                  // o local
            async_copy16(qt + (size_t)(bm * 64 + row) * H_DIM + kb + scol, As + q * 512);
        }
        for (int c = 0; c < 6; ++c) {
            int q = wid * 6 + c;                     // 0..23
            int row = q * 8 + srow;                  // bd row
            async_copy16(T + (size_t)row * H_DIM + kb + scol, Bs + q * 512);
        }
        __syncthreads();
        for (int kk = 0; kk < 64; kk += 32) {
            bf16x8 af[2], bf[6];
            int ko = kk + quad * 8;
            for (int t = 0; t < 2; ++t)
                af[t] = *(const bf16x8*)(As + (wave_m * 32 + t * 16 + cit) * 64 + ko);
            for (int t = 0; t < 6; ++t)
                bf[t] = *(const bf16x8*)(Bs + (wave_n * 96 + t * 16 + cit) * 64 + ko);
            for (int tm = 0; tm < 2; ++tm)
                for (int tn = 0; tn < 6; ++tn)
                    acc[tm][tn] = __builtin_amdgcn_mfma_f32_16x16x32_bf16(
                        af[tm], bf[tn], acc[tm][tn], 0, 0, 0);
        }
    }

    __syncthreads();                      // done with staging LDS; reuse for C tile
    float* cs = (float*)smem;             // [64][CS_PITCH]
    for (int tn = 0; tn < 6; ++tn) {
        int bd = wave_n * 96 + tn * 16 + cit;
        for (int tm = 0; tm < 2; ++tm) {
            int o0 = wave_m * 32 + tm * 16 + quad * 4;
            f32x4 c = acc[tm][tn];
            for (int r = 0; r < 4; ++r)
                cs[(o0 + r) * CS_PITCH + bd] = c[r];
        }
    }
    __syncthreads();
    // out[b][o][d]: 64 b's x (64 o x 3 d) = 12288 floats; contiguous 192-runs per b.
    for (int it = 0; it < 48; ++it) {
        int flat = it * 256 + tid;        // 0..12287
        int b = flat / NBD;
        int w = flat - b * NBD;           // o_l*3 + d
        int o_l = w / 3, d = w - o_l * 3;
        int og = bm * 64 + o_l;
        if (og < N_IN)
            out[(size_t)b * (N_IN * 3) + (size_t)og * 3 + d] =
                cs[o_l * CS_PITCH + b * 3 + d];
    }
}

extern "C" void kernel_launch(void* const* d_in, const int* in_sizes, int n_in,
                              void* d_out, int out_size, void* d_ws, size_t ws_size,
                              hipStream_t stream) {
    const float* x  = (const float*)d_in[0];
    const float* kw = (const float*)d_in[1];
    const float* qw = (const float*)d_in[2];
    const float* vw = (const float*)d_in[3];
    float* out = (float*)d_out;

    char* w = (char*)d_ws;
    short* keyb  = (short*)(w + 0);              // 5120*256*2 = 2,621,440
    short* qtb   = (short*)(w + 2621440);        // 5120*256*2 = 2,621,440
    short* keyT  = (short*)(w + 5242880);        // 256*5120*2 = 2,621,440
    short* vmatT = (short*)(w + 7864320);        // 192*5120*2 = 1,966,080
    float* l1    = (float*)(w + 9830400);        // 5120*4     = 20,480
    float* part2 = (float*)(w + 9850880);        // 20*192*256*4 = 3,932,160
    short* T     = (short*)(w + 13783040);       // 192*256*2  = 98,304
    // total: 13,881,344 bytes

    conv_key_all<<<dim3(H_DIM / 32, NPAD / 32), dim3(32, 8), 0, stream>>>(kw, keyb, keyT, l1);
    conv_qt<<<dim3(H_DIM / 32, NPAD / 32), dim3(32, 8), 0, stream>>>(qw, qtb);
    gemm_l1<<<dim3(NPAD / 128, NPAD / 128), 256, 0, stream>>>(qtb, keyb, l1);
    build_vmat<<<(B_SZ * NPAD) / 256, 256, 0, stream>>>(x, vw, l1, vmatT);
    gemm3<<<dim3(H_DIM / 64, SPLITZ), 256, 0, stream>>>(vmatT, keyT, part2);
    reduce_T<<<(NBD * H_DIM) / 256, 256, 0, stream>>>(part2, T);
    gemm4<<<NPAD / 64, 256, 0, stream>>>(qtb, T, out);
}

// Round 6
// 111.581 us; speedup vs baseline: 2.1283x; 1.0318x over previous
//
#include <hip/hip_runtime.h>
#include <hip/hip_bf16.h>

#define N_IN   5023
#define B_SZ   64
#define H_DIM  256
#define NPAD   5120
#define NBD    192          // B_SZ * 3
#define SPLITZ 20           // gemm3 split-K slices (K-chunk 256 = 4 x BK64)
#define OUT_ELEMS (B_SZ * N_IN * 3)   // 964416

typedef short bf16x8 __attribute__((ext_vector_type(8)));
typedef float f32x4  __attribute__((ext_vector_type(4)));

__device__ inline void async_copy16(const void* g, void* l) {
    __builtin_amdgcn_global_load_lds(
        (const __attribute__((address_space(1))) unsigned int*)g,
        (__attribute__((address_space(3))) unsigned int*)l,
        16, 0, 0);
}

// ---- key_w (5023x256 f32) -> keyb bf16 [5120][256] AND keyT bf16 [256][5120];
//      also zeroes l1. LDS-tiled transpose, both sides coalesced. ----
__global__ void conv_key_all(const float* __restrict__ kw, short* __restrict__ keyb,
                             short* __restrict__ keyT, float* __restrict__ l1) {
    __shared__ float tile[32][33];
    const int hb = blockIdx.x * 32;      // 8 tiles over H
    const int ib = blockIdx.y * 32;      // 160 tiles over NPAD
    const int tx = threadIdx.x;          // 32
    const int ty = threadIdx.y;          // 8
    __hip_bfloat16* kb = (__hip_bfloat16*)keyb;
    __hip_bfloat16* kt = (__hip_bfloat16*)keyT;
    for (int j = 0; j < 32; j += 8) {
        int i = ib + ty + j;
        int h = hb + tx;
        float v = (i < N_IN) ? kw[(size_t)i * H_DIM + h] : 0.0f;
        tile[ty + j][tx] = v;
        kb[(size_t)i * H_DIM + h] = __float2bfloat16(v);
    }
    __syncthreads();
    for (int j = 0; j < 32; j += 8) {
        int h = hb + ty + j;
        int i = ib + tx;
        kt[(size_t)h * NPAD + i] = __float2bfloat16(tile[tx][ty + j]);
    }
    if (blockIdx.x == 0 && ty == 0) l1[ib + tx] = 0.0f;
}

// ---- query_w (256x5023 f32) -> qt bf16 [5120][256] transposed *1/16, LDS tiled ----
__global__ void conv_qt(const float* __restrict__ qw, short* __restrict__ qtb) {
    __shared__ float tile[32][33];
    const int hb = blockIdx.x * 32;
    const int ob = blockIdx.y * 32;
    const int tx = threadIdx.x;
    const int ty = threadIdx.y;
    for (int j = 0; j < 32; j += 8) {
        int h = hb + ty + j;
        int o = ob + tx;
        tile[ty + j][tx] = (o < N_IN) ? qw[(size_t)h * N_IN + o] * 0.0625f : 0.0f;
    }
    __syncthreads();
    __hip_bfloat16* qt = (__hip_bfloat16*)qtb;
    for (int j = 0; j < 32; j += 8) {
        int o = ob + ty + j;
        int h = hb + tx;
        qt[(size_t)o * H_DIM + h] = __float2bfloat16(tile[tx][ty + j]);
    }
}

// ---- bf16 -> fp8 e4m3 for gemm_l1. q side un-scales the folded 1/16 (x16 exact)
//      so values sit in e4m3 normal range (sigma 0.0625). HW RNE via cvt_pk. ----
#define HALF_ELEMS (NPAD * H_DIM / 2)    // 655360 pairs per matrix
__global__ void conv_fp8(const short* __restrict__ qtb, const short* __restrict__ keyb,
                         unsigned short* __restrict__ q8, unsigned short* __restrict__ k8) {
    int idx = blockIdx.x * 256 + threadIdx.x;    // < 2*HALF_ELEMS
    bool isK = idx >= HALF_ELEMS;
    int p = isK ? idx - HALF_ELEMS : idx;
    const __hip_bfloat16* src = (const __hip_bfloat16*)(isK ? keyb : qtb);
    float a = __bfloat162float(src[2 * p]);
    float b = __bfloat162float(src[2 * p + 1]);
    if (!isK) { a *= 16.0f; b *= 16.0f; }
    int packed = __builtin_amdgcn_cvt_pk_fp8_f32(a, b, 0, false);
    (isK ? k8 : q8)[p] = (unsigned short)(packed & 0xFFFF);
}

// ---- GEMM_L1 (fp8): l1[i] = sum_o |sum_h q8[o][h]*k8[i][h]| (unscaled by 16^2;
//      folded out downstream). M=N=5120, K=256, tile 128x128, BK=128 (2 rounds),
//      LDS 2x16KB, XOR-swizzled 16B slots (key = row&7) to kill bank conflicts. ----
__launch_bounds__(256)
__global__ void gemm_l1(const unsigned char* __restrict__ q8,
                        const unsigned char* __restrict__ k8,
                        float* __restrict__ l1) {
    __shared__ unsigned char As8[128 * 128];   // 16 KB
    __shared__ unsigned char Bs8[128 * 128];   // 16 KB
    const int bm = blockIdx.x, bn = blockIdx.y;
    const int tid = threadIdx.x, lane = tid & 63, wid = tid >> 6;
    const int wave_m = wid >> 1, wave_n = wid & 1;
    const int r = lane >> 3;          // 0..7 row within chunk
    const int s = lane & 7;           // 0..7 16B slot
    const int quad = lane >> 4, cit = lane & 15;
    const int xk = cit & 7;           // fragment xor key (= row & 7)

    f32x4 acc[4][4];
    const f32x4 zf = {0.f, 0.f, 0.f, 0.f};
    for (int a = 0; a < 4; ++a)
        for (int b = 0; b < 4; ++b) acc[a][b] = zf;

    for (int kb = 0; kb < H_DIM; kb += 128) {
        __syncthreads();
        const int koff = kb + ((s ^ r) << 4);   // swizzled global k-group
        for (int c = 0; c < 4; ++c) {
            int q = wid * 4 + c;                // 1KB chunk 0..15 (8 rows each)
            int row = q * 8 + r;
            async_copy16(q8 + (size_t)(bm * 128 + row) * H_DIM + koff, As8 + q * 1024);
            async_copy16(k8 + (size_t)(bn * 128 + row) * H_DIM + koff, Bs8 + q * 1024);
        }
        __syncthreads();
        for (int ki = 0; ki < 4; ++ki) {        // 4 x K=32 per round
            int g = ki * 2 + (quad >> 1);       // global 16B group within row
            int lo8 = (quad & 1) << 3;
            int slot = ((g ^ xk) << 4) + lo8;
            long af[4], bf[4];
            for (int t = 0; t < 4; ++t) {
                int am = wave_m * 64 + t * 16 + cit;
                af[t] = *(const long*)(As8 + am * 128 + slot);
                int bn_ = wave_n * 64 + t * 16 + cit;
                bf[t] = *(const long*)(Bs8 + bn_ * 128 + slot);
            }
            for (int tm = 0; tm < 4; ++tm)
                for (int tn = 0; tn < 4; ++tn)
                    acc[tm][tn] = __builtin_amdgcn_mfma_f32_16x16x32_fp8_fp8(
                        af[tm], bf[tn], acc[tm][tn], 0, 0, 0);
        }
    }

    for (int tn = 0; tn < 4; ++tn) {
        int ig = bn * 128 + wave_n * 64 + tn * 16 + cit;   // column i
        float p = 0.0f;
        for (int tm = 0; tm < 4; ++tm) {
            f32x4 c = acc[tm][tn];
            p += fabsf(c.x) + fabsf(c.y) + fabsf(c.z) + fabsf(c.w);
        }
        p += __shfl_xor(p, 16);
        p += __shfl_xor(p, 32);
        if (quad == 0) atomicAdd(&l1[ig], p);
    }
}

// ---- vmatT[bd][i] = (1/max(l1u/16,eps)) * sum_d x[b,i,d]*vw[e,d], bf16 ----
// l1 holds the UNSCALED sum (score_u = 16*score), so rescale by 1/16 here.
__global__ void build_vmat(const float* __restrict__ x, const float* __restrict__ vw,
                           const float* __restrict__ l1, short* __restrict__ vmatT) {
    int idx = blockIdx.x * 256 + threadIdx.x;     // b*NPAD + i
    if (idx >= B_SZ * NPAD) return;
    int b = idx / NPAD, i = idx % NPAD;
    __hip_bfloat16* vt = (__hip_bfloat16*)vmatT;
    if (i < N_IN) {
        const float* xp = x + ((size_t)b * N_IN + i) * 3;
        float x0 = xp[0], x1 = xp[1], x2 = xp[2];
        float r = 1.0f / fmaxf(l1[i] * 0.0625f, 1e-12f);
        for (int e = 0; e < 3; ++e) {
            float v = x0 * vw[e * 3 + 0] + x1 * vw[e * 3 + 1] + x2 * vw[e * 3 + 2];
            vt[(size_t)(b * 3 + e) * NPAD + i] = __float2bfloat16(v * r);
        }
    } else {
        for (int e = 0; e < 3; ++e)
            vt[(size_t)(b * 3 + e) * NPAD + i] = __float2bfloat16(0.0f);
    }
}

// ---- GEMM3: part2[z][bd][h] = sum_{i in z-chunk} vmatT[bd][i] * keyT[h][i] ----
__launch_bounds__(256)
__global__ void gemm3(const short* __restrict__ vmatT, const short* __restrict__ keyT,
                      float* __restrict__ part2) {
    __shared__ short As[192 * 64];   // 24 KB
    __shared__ short Bs[64 * 64];    // 8 KB
    const int bh = blockIdx.x;       // h tile (4)
    const int z  = blockIdx.y;       // split-K (20)
    const int tid = threadIdx.x, lane = tid & 63, wid = tid >> 6;
    const int wave_m = wid >> 1, wave_n = wid & 1;
    const int srow = lane >> 3, scol = (lane & 7) * 8;
    const int quad = lane >> 4, cit = lane & 15;

    f32x4 acc[6][2];
    const f32x4 zf = {0.f, 0.f, 0.f, 0.f};
    for (int a = 0; a < 6; ++a)
        for (int b = 0; b < 2; ++b) acc[a][b] = zf;

    const int kbeg = z * (NPAD / SPLITZ);
    for (int kb = kbeg; kb < kbeg + NPAD / SPLITZ; kb += 64) {
        __syncthreads();
        for (int c = 0; c < 6; ++c) {
            int q = wid * 6 + c;
            int row = q * 8 + srow;
            async_copy16(vmatT + (size_t)row * NPAD + kb + scol, As + q * 512);
        }
        for (int c = 0; c < 2; ++c) {
            int q = wid * 2 + c;
            int row = q * 8 + srow;
            async_copy16(keyT + (size_t)(bh * 64 + row) * NPAD + kb + scol, Bs + q * 512);
        }
        __syncthreads();
        for (int kk = 0; kk < 64; kk += 32) {
            bf16x8 af[6], bf[2];
            int ko = kk + quad * 8;
            for (int t = 0; t < 6; ++t)
                af[t] = *(const bf16x8*)(As + (wave_m * 96 + t * 16 + cit) * 64 + ko);
            for (int t = 0; t < 2; ++t)
                bf[t] = *(const bf16x8*)(Bs + (wave_n * 32 + t * 16 + cit) * 64 + ko);
            for (int tm = 0; tm < 6; ++tm)
                for (int tn = 0; tn < 2; ++tn)
                    acc[tm][tn] = __builtin_amdgcn_mfma_f32_16x16x32_bf16(
                        af[tm], bf[tn], acc[tm][tn], 0, 0, 0);
        }
    }

    float* pz = part2 + (size_t)z * (NBD * H_DIM);
    for (int tn = 0; tn < 2; ++tn) {
        int h = bh * 64 + wave_n * 32 + tn * 16 + cit;
        for (int tm = 0; tm < 6; ++tm) {
            int bd0 = wave_m * 96 + tm * 16 + quad * 4;
            f32x4 c = acc[tm][tn];
            for (int r = 0; r < 4; ++r)
                pz[(size_t)(bd0 + r) * H_DIM + h] = c[r];
        }
    }
}

// ---- reduce_T: T[bd][h] = bf16(sum_z part2[z][bd][h]) ----
__global__ void reduce_T(const float* __restrict__ part2, short* __restrict__ T) {
    int idx = blockIdx.x * 256 + threadIdx.x;     // < 49152
    float s = 0.0f;
    for (int z = 0; z < SPLITZ; ++z)
        s += part2[(size_t)z * (NBD * H_DIM) + idx];
    ((__hip_bfloat16*)T)[idx] = __float2bfloat16(s);
}

// ---- GEMM4: y[o][bd] = sum_h qt[o][h] * T[bd][h]; out via LDS transpose ----
#define CS_PITCH 196
__launch_bounds__(256)
__global__ void gemm4(const short* __restrict__ qt, const short* __restrict__ T,
                      float* __restrict__ out) {
    __shared__ char smem[64 * CS_PITCH * 4];
    short* As = (short*)smem;                  // 64*64
    short* Bs = As + 64 * 64;                  // 192*64
    const int bm = blockIdx.x;                 // 80
    const int tid = threadIdx.x, lane = tid & 63, wid = tid >> 6;
    const int wave_m = wid >> 1, wave_n = wid & 1;
    const int srow = lane >> 3, scol = (lane & 7) * 8;
    const int quad = lane >> 4, cit = lane & 15;

    f32x4 acc[2][6];
    const f32x4 zf = {0.f, 0.f, 0.f, 0.f};
    for (int a = 0; a < 2; ++a)
        for (int b = 0; b < 6; ++b) acc[a][b] = zf;

    for (int kb = 0; kb < H_DIM; kb += 64) {
        __syncthreads();
        for (int c = 0; c < 2; ++c) {
            int q = wid * 2 + c;
            int row = q * 8 + srow;
            async_copy16(qt + (size_t)(bm * 64 + row) * H_DIM + kb + scol, As + q * 512);
        }
        for (int c = 0; c < 6; ++c) {
            int q = wid * 6 + c;
            int row = q * 8 + srow;
            async_copy16(T + (size_t)row * H_DIM + kb + scol, Bs + q * 512);
        }
        __syncthreads();
        for (int kk = 0; kk < 64; kk += 32) {
            bf16x8 af[2], bf[6];
            int ko = kk + quad * 8;
            for (int t = 0; t < 2; ++t)
                af[t] = *(const bf16x8*)(As + (wave_m * 32 + t * 16 + cit) * 64 + ko);
            for (int t = 0; t < 6; ++t)
                bf[t] = *(const bf16x8*)(Bs + (wave_n * 96 + t * 16 + cit) * 64 + ko);
            for (int tm = 0; tm < 2; ++tm)
                for (int tn = 0; tn < 6; ++tn)
                    acc[tm][tn] = __builtin_amdgcn_mfma_f32_16x16x32_bf16(
                        af[tm], bf[tn], acc[tm][tn], 0, 0, 0);
        }
    }

    __syncthreads();
    float* cs = (float*)smem;             // [64][CS_PITCH]
    for (int tn = 0; tn < 6; ++tn) {
        int bd = wave_n * 96 + tn * 16 + cit;
        for (int tm = 0; tm < 2; ++tm) {
            int o0 = wave_m * 32 + tm * 16 + quad * 4;
            f32x4 c = acc[tm][tn];
            for (int r = 0; r < 4; ++r)
                cs[(o0 + r) * CS_PITCH + bd] = c[r];
        }
    }
    __syncthreads();
    for (int it = 0; it < 48; ++it) {
        int flat = it * 256 + tid;        // 0..12287
        int b = flat / NBD;
        int w = flat - b * NBD;
        int o_l = w / 3, d = w - o_l * 3;
        int og = bm * 64 + o_l;
        if (og < N_IN)
            out[(size_t)b * (N_IN * 3) + (size_t)og * 3 + d] =
                cs[o_l * CS_PITCH + b * 3 + d];
    }
}

extern "C" void kernel_launch(void* const* d_in, const int* in_sizes, int n_in,
                              void* d_out, int out_size, void* d_ws, size_t ws_size,
                              hipStream_t stream) {
    const float* x  = (const float*)d_in[0];
    const float* kw = (const float*)d_in[1];
    const float* qw = (const float*)d_in[2];
    const float* vw = (const float*)d_in[3];
    float* out = (float*)d_out;

    char* w = (char*)d_ws;
    short* keyb  = (short*)(w + 0);              // 5120*256*2 = 2,621,440
    short* qtb   = (short*)(w + 2621440);        // 5120*256*2 = 2,621,440
    short* keyT  = (short*)(w + 5242880);        // 256*5120*2 = 2,621,440
    short* vmatT = (short*)(w + 7864320);        // 192*5120*2 = 1,966,080
    float* l1    = (float*)(w + 9830400);        // 5120*4     = 20,480
    float* part2 = (float*)(w + 9850880);        // 20*192*256*4 = 3,932,160
    short* T     = (short*)(w + 13783040);       // 192*256*2  = 98,304
    unsigned short* q8 = (unsigned short*)(w + 13881344);  // 5120*256 = 1,310,720
    unsigned short* k8 = (unsigned short*)(w + 15192064);  // 5120*256 = 1,310,720
    // total: 16,502,784 bytes

    conv_key_all<<<dim3(H_DIM / 32, NPAD / 32), dim3(32, 8), 0, stream>>>(kw, keyb, keyT, l1);
    conv_qt<<<dim3(H_DIM / 32, NPAD / 32), dim3(32, 8), 0, stream>>>(qw, qtb);
    conv_fp8<<<(2 * HALF_ELEMS) / 256, 256, 0, stream>>>(qtb, keyb, q8, k8);
    gemm_l1<<<dim3(NPAD / 128, NPAD / 128), 256, 0, stream>>>(
        (const unsigned char*)q8, (const unsigned char*)k8, l1);
    build_vmat<<<(B_SZ * NPAD) / 256, 256, 0, stream>>>(x, vw, l1, vmatT);
    gemm3<<<dim3(H_DIM / 64, SPLITZ), 256, 0, stream>>>(vmatT, keyT, part2);
    reduce_T<<<(NBD * H_DIM) / 256, 256, 0, stream>>>(part2, T);
    gemm4<<<NPAD / 64, 256, 0, stream>>>(qtb, T, out);
}

// Round 7
// 107.399 us; speedup vs baseline: 2.2111x; 1.0389x over previous
//
#include <hip/hip_runtime.h>
#include <hip/hip_bf16.h>

#define N_IN   5023
#define B_SZ   64
#define H_DIM  256
#define NPAD   5120
#define NBD    192          // B_SZ * 3
#define SPLITZ 80           // gemm3 split-K slices, 64-wide chunks
#define OUT_ELEMS (B_SZ * N_IN * 3)   // 964416

typedef short bf16x8 __attribute__((ext_vector_type(8)));
typedef float f32x4  __attribute__((ext_vector_type(4)));

__device__ inline void async_copy16(const void* g, void* l) {
    __builtin_amdgcn_global_load_lds(
        (const __attribute__((address_space(1))) unsigned int*)g,
        (__attribute__((address_space(3))) unsigned int*)l,
        16, 0, 0);
}

__device__ inline unsigned char to_fp8(float v) {
    int p = __builtin_amdgcn_cvt_pk_fp8_f32(v, 0.0f, 0, false);
    return (unsigned char)(p & 0xFF);
}

// ---- conv_all: z=0: key_w[i][h] -> k8 fp8 [5120][256] + keyT bf16 [256][5120]
//                z=1: query_w[h][o] -> q8 fp8 [5120][256] + qtb bf16 [5120][256] (*1/16)
//      q8/k8 hold UNSCALED values (sigma 0.0625, e4m3 normal range).
//      Also zeroes l1 (z=0 blocks). ----
__global__ void conv_all(const float* __restrict__ kw, const float* __restrict__ qw,
                         unsigned char* __restrict__ k8, short* __restrict__ keyT,
                         unsigned char* __restrict__ q8, short* __restrict__ qtb,
                         float* __restrict__ l1) {
    __shared__ float tile[32][33];
    const int hb = blockIdx.x * 32;      // 8 tiles over H
    const int nb = blockIdx.y * 32;      // 160 tiles over NPAD
    const int tx = threadIdx.x;          // 32
    const int ty = threadIdx.y;          // 8
    if (blockIdx.z == 0) {
        // key: read [i][h] coalesced; k8 straight; keyT transposed.
        for (int j = 0; j < 32; j += 8) {
            int i = nb + ty + j;
            int h = hb + tx;
            float v = (i < N_IN) ? kw[(size_t)i * H_DIM + h] : 0.0f;
            tile[ty + j][tx] = v;
            k8[(size_t)i * H_DIM + h] = to_fp8(v);
        }
        __syncthreads();
        __hip_bfloat16* kt = (__hip_bfloat16*)keyT;
        for (int j = 0; j < 32; j += 8) {
            int h = hb + ty + j;
            int i = nb + tx;
            kt[(size_t)h * NPAD + i] = __float2bfloat16(tile[tx][ty + j]);
        }
        if (blockIdx.x == 0 && ty == 0) l1[nb + tx] = 0.0f;
    } else {
        // query: read [h][o] coalesced; q8 + qtb from transposed side.
        for (int j = 0; j < 32; j += 8) {
            int h = hb + ty + j;
            int o = nb + tx;
            tile[ty + j][tx] = (o < N_IN) ? qw[(size_t)h * N_IN + o] : 0.0f;
        }
        __syncthreads();
        __hip_bfloat16* qt = (__hip_bfloat16*)qtb;
        for (int j = 0; j < 32; j += 8) {
            int o = nb + ty + j;
            int h = hb + tx;
            float v = tile[tx][ty + j];
            qt[(size_t)o * H_DIM + h] = __float2bfloat16(v * 0.0625f);
            q8[(size_t)o * H_DIM + h] = to_fp8(v);
        }
    }
}

// ---- GEMM_L1 (fp8): l1[i] = sum_o |sum_h q8[o][h]*k8[i][h]| (unscaled by 16^2;
//      folded out downstream). M=N=5120, K=256, tile 128x128, BK=128 (2 rounds),
//      LDS 2x16KB, XOR-swizzled 16B slots (key = row&7). ----
__launch_bounds__(256)
__global__ void gemm_l1(const unsigned char* __restrict__ q8,
                        const unsigned char* __restrict__ k8,
                        float* __restrict__ l1) {
    __shared__ unsigned char As8[128 * 128];   // 16 KB
    __shared__ unsigned char Bs8[128 * 128];   // 16 KB
    const int bm = blockIdx.x, bn = blockIdx.y;
    const int tid = threadIdx.x, lane = tid & 63, wid = tid >> 6;
    const int wave_m = wid >> 1, wave_n = wid & 1;
    const int r = lane >> 3;          // 0..7 row within chunk
    const int s = lane & 7;           // 0..7 16B slot
    const int quad = lane >> 4, cit = lane & 15;
    const int xk = cit & 7;           // fragment xor key (= row & 7)

    f32x4 acc[4][4];
    const f32x4 zf = {0.f, 0.f, 0.f, 0.f};
    for (int a = 0; a < 4; ++a)
        for (int b = 0; b < 4; ++b) acc[a][b] = zf;

    for (int kb = 0; kb < H_DIM; kb += 128) {
        __syncthreads();
        const int koff = kb + ((s ^ r) << 4);   // swizzled global k-group
        for (int c = 0; c < 4; ++c) {
            int q = wid * 4 + c;                // 1KB chunk 0..15 (8 rows each)
            int row = q * 8 + r;
            async_copy16(q8 + (size_t)(bm * 128 + row) * H_DIM + koff, As8 + q * 1024);
            async_copy16(k8 + (size_t)(bn * 128 + row) * H_DIM + koff, Bs8 + q * 1024);
        }
        __syncthreads();
        for (int ki = 0; ki < 4; ++ki) {        // 4 x K=32 per round
            int g = ki * 2 + (quad >> 1);       // global 16B group within row
            int lo8 = (quad & 1) << 3;
            int slot = ((g ^ xk) << 4) + lo8;
            long af[4], bf[4];
            for (int t = 0; t < 4; ++t) {
                int am = wave_m * 64 + t * 16 + cit;
                af[t] = *(const long*)(As8 + am * 128 + slot);
                int bn_ = wave_n * 64 + t * 16 + cit;
                bf[t] = *(const long*)(Bs8 + bn_ * 128 + slot);
            }
            for (int tm = 0; tm < 4; ++tm)
                for (int tn = 0; tn < 4; ++tn)
                    acc[tm][tn] = __builtin_amdgcn_mfma_f32_16x16x32_fp8_fp8(
                        af[tm], bf[tn], acc[tm][tn], 0, 0, 0);
        }
    }

    for (int tn = 0; tn < 4; ++tn) {
        int ig = bn * 128 + wave_n * 64 + tn * 16 + cit;   // column i
        float p = 0.0f;
        for (int tm = 0; tm < 4; ++tm) {
            f32x4 c = acc[tm][tn];
            p += fabsf(c.x) + fabsf(c.y) + fabsf(c.z) + fabsf(c.w);
        }
        p += __shfl_xor(p, 16);
        p += __shfl_xor(p, 32);
        if (quad == 0) atomicAdd(&l1[ig], p);
    }
}

// ---- GEMM3_F (build_vmat fused): part2[z][bd][h] =
//      sum_{i in 64-chunk} vmat[bd][i] * keyT[h][i],
//      vmat[b*3+e][i] = (1/max(l1[i]/16,eps)) * sum_d x[b,i,d]*vw[e,d]
//      computed directly into padded LDS (pitch 72 -> +4-bank row shift).
//      Grid (4 h-tiles, 80 z). Waves 2x2: wave tile 96x32. ----
#define AP 72    // As pitch in bf16: 144 B = 9*16 (aligned), 36 dw = +4 banks/row
__launch_bounds__(256)
__global__ void gemm3_f(const float* __restrict__ x, const float* __restrict__ vw,
                        const float* __restrict__ l1, const short* __restrict__ keyT,
                        float* __restrict__ part2) {
    __shared__ short As[NBD * AP];    // 27,648 B
    __shared__ short Bs[64 * 64];     // 8,192 B (XOR-swizzled 16B slots)
    const int bh = blockIdx.x;        // h tile (4)
    const int z  = blockIdx.y;        // i chunk (80)
    const int tid = threadIdx.x, lane = tid & 63, wid = tid >> 6;
    const int wave_m = wid >> 1, wave_n = wid & 1;
    const int rr = lane >> 3, ss = lane & 7;
    const int quad = lane >> 4, cit = lane & 15;

    // ---- build vmat tile into As ----
    {
        const int i_loc = tid & 63;
        const int grp   = tid >> 6;            // 4 groups x 16 b
        const int i = z * 64 + i_loc;
        const bool ok = (i < N_IN);
        float rcp = 0.0f;
        if (ok) rcp = 1.0f / fmaxf(l1[i] * 0.0625f, 1e-12f);
        float w00 = vw[0], w01 = vw[1], w02 = vw[2];
        float w10 = vw[3], w11 = vw[4], w12 = vw[5];
        float w20 = vw[6], w21 = vw[7], w22 = vw[8];
        __hip_bfloat16* as = (__hip_bfloat16*)As;
        for (int bo = 0; bo < 16; ++bo) {
            int b = grp * 16 + bo;
            float x0 = 0.f, x1 = 0.f, x2 = 0.f;
            if (ok) {
                const float* xp = x + ((size_t)b * N_IN + i) * 3;
                x0 = xp[0]; x1 = xp[1]; x2 = xp[2];
            }
            as[(b * 3 + 0) * AP + i_loc] = __float2bfloat16((x0 * w00 + x1 * w01 + x2 * w02) * rcp);
            as[(b * 3 + 1) * AP + i_loc] = __float2bfloat16((x0 * w10 + x1 * w11 + x2 * w12) * rcp);
            as[(b * 3 + 2) * AP + i_loc] = __float2bfloat16((x0 * w20 + x1 * w21 + x2 * w22) * rcp);
        }
    }
    // ---- stage Bs (keyT rows, swizzled) ----
    for (int c = 0; c < 2; ++c) {
        int q = wid * 2 + c;                   // 0..7 (1KB chunks)
        int row = q * 8 + rr;                  // h local 0..63
        int koff = z * 64 + ((ss ^ (rr & 7)) << 3);
        async_copy16(keyT + (size_t)(bh * 64 + row) * NPAD + koff, Bs + q * 512);
    }
    __syncthreads();

    f32x4 acc[6][2];
    const f32x4 zf = {0.f, 0.f, 0.f, 0.f};
    for (int a = 0; a < 6; ++a)
        for (int b = 0; b < 2; ++b) acc[a][b] = zf;

    for (int kk = 0; kk < 64; kk += 32) {
        bf16x8 af[6], bf[2];
        int g = (kk >> 3) + quad;
        for (int t = 0; t < 6; ++t) {
            int row = wave_m * 96 + t * 16 + cit;
            af[t] = *(const bf16x8*)(As + row * AP + kk + quad * 8);
        }
        for (int t = 0; t < 2; ++t) {
            int row = wave_n * 32 + t * 16 + cit;
            bf[t] = *(const bf16x8*)(Bs + row * 64 + ((g ^ (cit & 7)) << 3));
        }
        for (int tm = 0; tm < 6; ++tm)
            for (int tn = 0; tn < 2; ++tn)
                acc[tm][tn] = __builtin_amdgcn_mfma_f32_16x16x32_bf16(
                    af[tm], bf[tn], acc[tm][tn], 0, 0, 0);
    }

    float* pz = part2 + (size_t)z * (NBD * H_DIM);
    for (int tn = 0; tn < 2; ++tn) {
        int h = bh * 64 + wave_n * 32 + tn * 16 + cit;
        for (int tm = 0; tm < 6; ++tm) {
            int bd0 = wave_m * 96 + tm * 16 + quad * 4;
            f32x4 c = acc[tm][tn];
            for (int r2 = 0; r2 < 4; ++r2)
                pz[(size_t)(bd0 + r2) * H_DIM + h] = c[r2];
        }
    }
}

// ---- reduce_T: T[bd][h] = bf16(sum_z part2[z][bd][h]) ----
__global__ void reduce_T(const float* __restrict__ part2, short* __restrict__ T) {
    int idx = blockIdx.x * 256 + threadIdx.x;     // < 49152
    float s = 0.0f;
    for (int z = 0; z < SPLITZ; ++z)
        s += part2[(size_t)z * (NBD * H_DIM) + idx];
    ((__hip_bfloat16*)T)[idx] = __float2bfloat16(s);
}

// ---- GEMM4: y[o][bd] = sum_h qt[o][h] * T[bd][h]; out via LDS transpose.
//      M-tile 32 -> 160 blocks. Waves 2x2: wave tile 16x96. XOR-swizzled LDS. ----
#define CS_PITCH 196
__launch_bounds__(256)
__global__ void gemm4(const short* __restrict__ qt, const short* __restrict__ T,
                      float* __restrict__ out) {
    __shared__ __align__(16) char smem[28672];   // staging 28KB / CS 25KB union
    short* As = (short*)smem;                    // 32 x 64 (4 KB, swizzled)
    short* Bs = (short*)(smem + 4096);           // 192 x 64 (24 KB, swizzled)
    const int bm = blockIdx.x;                   // 160
    const int tid = threadIdx.x, lane = tid & 63, wid = tid >> 6;
    const int wave_m = wid >> 1, wave_n = wid & 1;
    const int rr = lane >> 3, ss = lane & 7;
    const int quad = lane >> 4, cit = lane & 15;

    f32x4 acc[6];
    const f32x4 zf = {0.f, 0.f, 0.f, 0.f};
    for (int b = 0; b < 6; ++b) acc[b] = zf;

    for (int kb = 0; kb < H_DIM; kb += 64) {
        __syncthreads();
        const int koff = kb + ((ss ^ (rr & 7)) << 3);
        {   // As: 4 chunks, one per wave
            int row = wid * 8 + rr;              // 0..31
            async_copy16(qt + (size_t)(bm * 32 + row) * H_DIM + koff, As + wid * 512);
        }
        for (int c = 0; c < 6; ++c) {            // Bs: 24 chunks
            int q = wid * 6 + c;
            int row = q * 8 + rr;                // 0..191
            async_copy16(T + (size_t)row * H_DIM + koff, Bs + q * 512);
        }
        __syncthreads();
        for (int kk = 0; kk < 64; kk += 32) {
            bf16x8 af, bf[6];
            int g = (kk >> 3) + quad;
            int slot = (g ^ (cit & 7)) << 3;
            {
                int row = wave_m * 16 + cit;
                af = *(const bf16x8*)(As + row * 64 + slot);
            }
            for (int t = 0; t < 6; ++t) {
                int row = wave_n * 96 + t * 16 + cit;
                bf[t] = *(const bf16x8*)(Bs + row * 64 + slot);
            }
            for (int tn = 0; tn < 6; ++tn)
                acc[tn] = __builtin_amdgcn_mfma_f32_16x16x32_bf16(
                    af, bf[tn], acc[tn], 0, 0, 0);
        }
    }

    __syncthreads();
    float* cs = (float*)smem;             // [32][CS_PITCH]
    for (int tn = 0; tn < 6; ++tn) {
        int bd = wave_n * 96 + tn * 16 + cit;
        int o0 = wave_m * 16 + quad * 4;
        f32x4 c = acc[tn];
        for (int r2 = 0; r2 < 4; ++r2)
            cs[(o0 + r2) * CS_PITCH + bd] = c[r2];
    }
    __syncthreads();
    // out[b][o][d]: 64 b x (32 o x 3 d) = 6144 floats; 96-float runs per b.
    for (int it = 0; it < 24; ++it) {
        int flat = it * 256 + tid;        // 0..6143
        int b = flat / 96;
        int w = flat - b * 96;
        int o_l = w / 3, d = w - o_l * 3;
        int og = bm * 32 + o_l;
        if (og < N_IN)
            out[(size_t)b * (N_IN * 3) + (size_t)og * 3 + d] =
                cs[o_l * CS_PITCH + b * 3 + d];
    }
}

extern "C" void kernel_launch(void* const* d_in, const int* in_sizes, int n_in,
                              void* d_out, int out_size, void* d_ws, size_t ws_size,
                              hipStream_t stream) {
    const float* x  = (const float*)d_in[0];
    const float* kw = (const float*)d_in[1];
    const float* qw = (const float*)d_in[2];
    const float* vw = (const float*)d_in[3];
    float* out = (float*)d_out;

    char* w = (char*)d_ws;
    short* qtb  = (short*)(w + 0);                        // 5120*256*2 = 2,621,440
    short* keyT = (short*)(w + 2621440);                  // 256*5120*2 = 2,621,440
    unsigned char* q8 = (unsigned char*)(w + 5242880);    // 5120*256   = 1,310,720
    unsigned char* k8 = (unsigned char*)(w + 6553600);    // 5120*256   = 1,310,720
    float* l1    = (float*)(w + 7864320);                 // 5120*4     = 20,480
    float* part2 = (float*)(w + 7884800);                 // 80*192*256*4 = 15,728,640
    short* T     = (short*)(w + 23613440);                // 192*256*2  = 98,304
    // total: 23,711,744 bytes

    conv_all<<<dim3(H_DIM / 32, NPAD / 32, 2), dim3(32, 8), 0, stream>>>(
        kw, qw, k8, keyT, q8, qtb, l1);
    gemm_l1<<<dim3(NPAD / 128, NPAD / 128), 256, 0, stream>>>(q8, k8, l1);
    gemm3_f<<<dim3(H_DIM / 64, SPLITZ), 256, 0, stream>>>(x, vw, l1, keyT, part2);
    reduce_T<<<(NBD * H_DIM) / 256, 256, 0, stream>>>(part2, T);
    gemm4<<<NPAD / 32, 256, 0, stream>>>(qtb, T, out);
}